// Round 1
// baseline (519.795 us; speedup 1.0000x reference)
//
#include <hip/hip_runtime.h>

#define N_ACT 80
#define M_CON 85
#define NP1 81          // n+1 (z = [x; r])
#define G_STRIDE 81     // odd stride -> conflict-free column reads (2-way only)
#define PDHG_ITERS 200
#define POWER_ITERS 20
#define BLOCK 128

__device__ __forceinline__ float wave_reduce_sum(float v) {
#pragma unroll
    for (int off = 32; off > 0; off >>= 1) v += __shfl_down(v, off, 64);
    return v;
}
__device__ __forceinline__ float wave_reduce_min(float v) {
#pragma unroll
    for (int off = 32; off > 0; off >>= 1) v = fminf(v, __shfl_down(v, off, 64));
    return v;
}

__global__ __launch_bounds__(BLOCK) void cheby_proj_kernel(
    const float* __restrict__ x_hat, const float* __restrict__ A,
    const float* __restrict__ b, float* __restrict__ out)
{
    // G[i][j] for j<80 is A; G[i][80] = d_i (row norm). Stride 81 floats.
    __shared__ float G[M_CON * G_STRIDE];            // 27540 B
    __shared__ __align__(16) float yv[88];           // y (PDHG dual) / g (power)
    __shared__ __align__(16) float zbv[84];          // z_bar / v (power)
    __shared__ __align__(16) float bl[88];           // b
    __shared__ __align__(16) float dv[80];           // dvec = x_hat - x0
    __shared__ float red[2];                         // cross-wave reduce scratch

    const int tid = threadIdx.x;
    const int p = blockIdx.x;

    // ---- stage A -> LDS (coalesced), load b ----
    const float* Ap = A + (size_t)p * (M_CON * N_ACT);
    for (int idx = tid; idx < M_CON * N_ACT; idx += BLOCK) {
        int r = idx / N_ACT;
        int c = idx - r * N_ACT;
        G[r * G_STRIDE + c] = Ap[idx];
    }
    if (tid < M_CON) bl[tid] = b[(size_t)p * M_CON + tid];
    __syncthreads();

    // ---- d = clip(||A_i||_2, 1e-12) -> column 80 of G ----
    if (tid < M_CON) {
        const float* row = &G[tid * G_STRIDE];
        float s = 0.f;
#pragma unroll
        for (int j = 0; j < N_ACT; ++j) s += row[j] * row[j];
        G[tid * G_STRIDE + N_ACT] = fmaxf(sqrtf(s), 1e-12f);
    }
    if (tid < NP1) zbv[tid] = 1.0f;   // v = ones(n+1)
    __syncthreads();

    // ---- power iteration: v <- GT(G v) / ||.|| ----
#pragma unroll 1
    for (int it = 0; it < POWER_ITERS; ++it) {
        if (tid < M_CON) {            // g = G v
            const float* row = &G[tid * G_STRIDE];
            float g = 0.f;
#pragma unroll
            for (int k = 0; k < 20; ++k) {
                float4 v4 = *(const float4*)&zbv[4 * k];
                g += row[4*k]*v4.x + row[4*k+1]*v4.y + row[4*k+2]*v4.z + row[4*k+3]*v4.w;
            }
            g += row[80] * zbv[80];
            yv[tid] = g;
        }
        __syncthreads();
        float w = 0.f;
        if (tid < NP1) {              // w = GT g
            const float* col = &G[tid];
#pragma unroll
            for (int k = 0; k < 21; ++k) {
                float4 g4 = *(const float4*)&yv[4 * k];
                w += col[(4*k)*G_STRIDE]*g4.x + col[(4*k+1)*G_STRIDE]*g4.y
                   + col[(4*k+2)*G_STRIDE]*g4.z + col[(4*k+3)*G_STRIDE]*g4.w;
            }
            w += col[84 * G_STRIDE] * yv[84];
        }
        float s = wave_reduce_sum((tid < NP1) ? w * w : 0.f);
        if ((tid & 63) == 0) red[tid >> 6] = s;
        __syncthreads();
        float nrm = sqrtf(red[0] + red[1]);
        if (tid < NP1) zbv[tid] = w / (nrm + 1e-12f);
        __syncthreads();
    }

    // ---- L = ||G v||, tau = sigma = 0.9 / max(L,1e-6) ----
    float tau;
    {
        float g = 0.f;
        if (tid < M_CON) {
            const float* row = &G[tid * G_STRIDE];
#pragma unroll
            for (int k = 0; k < 20; ++k) {
                float4 v4 = *(const float4*)&zbv[4 * k];
                g += row[4*k]*v4.x + row[4*k+1]*v4.y + row[4*k+2]*v4.z + row[4*k+3]*v4.w;
            }
            g += row[80] * zbv[80];
        }
        float s = wave_reduce_sum((tid < M_CON) ? g * g : 0.f);
        if ((tid & 63) == 0) red[tid >> 6] = s;
        __syncthreads();
        float L = sqrtf(red[0] + red[1]);
        tau = 0.9f / fmaxf(L, 1e-6f);
    }

    // ---- PDHG: z (per-thread reg, tid<81), y in LDS ----
    if (tid < M_CON) yv[tid] = 0.f;
    float z = 0.f;
    __syncthreads();

#pragma unroll 1
    for (int it = 0; it < PDHG_ITERS; ++it) {
        if (tid < NP1) {
            const float* col = &G[tid];
            float gt = 0.f;
#pragma unroll
            for (int k = 0; k < 21; ++k) {
                float4 y4 = *(const float4*)&yv[4 * k];
                gt += col[(4*k)*G_STRIDE]*y4.x + col[(4*k+1)*G_STRIDE]*y4.y
                    + col[(4*k+2)*G_STRIDE]*y4.z + col[(4*k+3)*G_STRIDE]*y4.w;
            }
            gt += col[84 * G_STRIDE] * yv[84];
            float cj = (tid == N_ACT) ? -1.0f : 0.0f;
            float zn = fmaxf(z - tau * (cj + gt), 0.f);
            zbv[tid] = 2.f * zn - z;   // extrapolation
            z = zn;
        }
        __syncthreads();
        if (tid < M_CON) {
            const float* row = &G[tid * G_STRIDE];
            float gz = 0.f;
#pragma unroll
            for (int k = 0; k < 20; ++k) {
                float4 v4 = *(const float4*)&zbv[4 * k];
                gz += row[4*k]*v4.x + row[4*k+1]*v4.y + row[4*k+2]*v4.z + row[4*k+3]*v4.w;
            }
            gz += row[80] * zbv[80];
            yv[tid] = fmaxf(yv[tid] + tau * (gz - bl[tid]), 0.f);
        }
        __syncthreads();
    }

    // ---- alpha map ----
    if (tid < N_ACT) {
        float x0 = z;                 // thread j<80 owns x0_j
        zbv[tid] = x0;
        dv[tid] = x_hat[(size_t)p * N_ACT + tid] - x0;
    }
    __syncthreads();

    const float FINF = __builtin_inff();
    float av = FINF;
    if (tid < M_CON) {
        const float* row = &G[tid * G_STRIDE];
        float ax0 = 0.f, ad = 0.f;
#pragma unroll
        for (int k = 0; k < 20; ++k) {
            float4 x4 = *(const float4*)&zbv[4 * k];
            float4 d4 = *(const float4*)&dv[4 * k];
            float a0 = row[4*k], a1 = row[4*k+1], a2 = row[4*k+2], a3 = row[4*k+3];
            ax0 += a0*x4.x + a1*x4.y + a2*x4.z + a3*x4.w;
            ad  += a0*d4.x + a1*d4.y + a2*d4.z + a3*d4.w;
        }
        float slack = fmaxf(bl[tid] - ax0, 0.f);
        av = (ad > 0.f) ? slack / (ad + 1e-12f) : FINF;
    }
    float m = wave_reduce_min(av);
    if ((tid & 63) == 0) red[tid >> 6] = m;
    __syncthreads();
    float alpha = fminf(red[0], red[1]);
    alpha = (alpha < FINF) ? alpha : 1.0f;       // !isfinite (inf or NaN) -> 1.0
    alpha = fminf(fmaxf(alpha - 1e-9f, 0.f), 1.0f);

    if (tid < N_ACT) {
        out[(size_t)p * N_ACT + tid] = fmaxf(zbv[tid] + alpha * dv[tid], 0.f);
    }
}

extern "C" void kernel_launch(void* const* d_in, const int* in_sizes, int n_in,
                              void* d_out, int out_size, void* d_ws, size_t ws_size,
                              hipStream_t stream) {
    const float* x_hat = (const float*)d_in[0];
    const float* A     = (const float*)d_in[1];
    const float* b     = (const float*)d_in[2];
    float* out = (float*)d_out;
    int P = in_sizes[0] / N_ACT;   // B*S = 1024
    cheby_proj_kernel<<<P, BLOCK, 0, stream>>>(x_hat, A, b, out);
}

// Round 2
// 427.385 us; speedup vs baseline: 1.2162x; 1.2162x over previous
//
#include <hip/hip_runtime.h>

#define N_ACT 80
#define M_CON 85
#define PDHG_ITERS 200
#define POWER_ITERS 20
#define NR 11   // row slots per lane: i = ti + 8r
#define NC 11   // col slots per lane: j = tj + 8c

// lane layout: l = ti*8 + tj; ti = l>>3 (rows), tj = l&7 (cols)
// row-dot reduction: sum over tj  -> shfl_xor masks 1,2,4
// col-dot reduction: sum over ti  -> shfl_xor masks 8,16,32

__device__ __forceinline__ float rsum_cols(float v) {  // across tj
    v += __shfl_xor(v, 1, 64);
    v += __shfl_xor(v, 2, 64);
    v += __shfl_xor(v, 4, 64);
    return v;
}
__device__ __forceinline__ float rsum_rows(float v) {  // across ti
    v += __shfl_xor(v, 8, 64);
    v += __shfl_xor(v, 16, 64);
    v += __shfl_xor(v, 32, 64);
    return v;
}

__global__ __launch_bounds__(64) void cheby_proj_kernel(
    const float* __restrict__ x_hat, const float* __restrict__ A,
    const float* __restrict__ b, float* __restrict__ out)
{
    const int p  = blockIdx.x;
    const int l  = threadIdx.x;
    const int tj = l & 7;
    const int ti = l >> 3;

    // ---- load G fragment: g[r][c] = G[ti+8r][tj+8c]; col slot 10 = d ----
    float g[NR][NC];
    float bl[NR];
    const float* Ap = A + (size_t)p * (M_CON * N_ACT);
#pragma unroll
    for (int r = 0; r < NR; ++r) {
        const int i = ti + 8 * r;
        const bool vi = (i < M_CON);
#pragma unroll
        for (int c = 0; c < 10; ++c) {
            const int j = tj + 8 * c;               // j <= 79: always valid
            g[r][c] = vi ? Ap[i * N_ACT + j] : 0.f;
        }
        g[r][10] = 0.f;
        bl[r] = vi ? b[(size_t)p * M_CON + i] : 1e30f;
    }

    // ---- d_i = max(||A_i||, 1e-12) -> col slot 10 (j==80) on tj==0 ----
#pragma unroll
    for (int r = 0; r < NR; ++r) {
        float s = 0.f;
#pragma unroll
        for (int c = 0; c < 10; ++c) s += g[r][c] * g[r][c];
        s = rsum_cols(s);
        const int i = ti + 8 * r;
        if (tj == 0 && i < M_CON) g[r][10] = fmaxf(sqrtf(s), 1e-12f);
    }

    // ---- power iteration: v <- GT(G v)/||.||, v0 = ones(n+1) ----
    float v[NC];
#pragma unroll
    for (int c = 0; c < NC; ++c) {
        const int j = tj + 8 * c;
        v[c] = (j <= N_ACT) ? 1.f : 0.f;
    }
#pragma unroll 1
    for (int it = 0; it < POWER_ITERS; ++it) {
        float gi[NR];
#pragma unroll
        for (int r = 0; r < NR; ++r) {
            float s = 0.f;
#pragma unroll
            for (int c = 0; c < NC; ++c) s += g[r][c] * v[c];
            gi[r] = rsum_cols(s);                   // replicated across tj
        }
        float nrm = 0.f;
        float w[NC];
#pragma unroll
        for (int c = 0; c < NC; ++c) {
            float s = 0.f;
#pragma unroll
            for (int r = 0; r < NR; ++r) s += g[r][c] * gi[r];
            s = rsum_rows(s);                       // replicated across ti
            w[c] = s;
            nrm += s * s;
        }
        nrm = rsum_cols(nrm);                       // total ||w||^2
        const float inv = 1.f / (sqrtf(nrm) + 1e-12f);
#pragma unroll
        for (int c = 0; c < NC; ++c) v[c] = w[c] * inv;
    }

    // ---- L = ||G v||; tau = sigma = 0.9/max(L,1e-6) ----
    float tau;
    {
        float L2 = 0.f;
#pragma unroll
        for (int r = 0; r < NR; ++r) {
            float s = 0.f;
#pragma unroll
            for (int c = 0; c < NC; ++c) s += g[r][c] * v[c];
            s = rsum_cols(s);
            L2 += s * s;
        }
        L2 = rsum_rows(L2);
        tau = 0.9f / fmaxf(sqrtf(L2), 1e-6f);
    }

    // ---- PDHG: z[c] replicated across ti, y[r] replicated across tj ----
    float z[NC], y[NR];
#pragma unroll
    for (int c = 0; c < NC; ++c) z[c] = 0.f;
#pragma unroll
    for (int r = 0; r < NR; ++r) y[r] = 0.f;

#pragma unroll 1
    for (int it = 0; it < PDHG_ITERS; ++it) {
        // z_new = relu(z - tau*(c + GT y)); zbar = 2 z_new - z
        float zb[NC];
#pragma unroll
        for (int c = 0; c < NC; ++c) {
            float s = 0.f;
#pragma unroll
            for (int r = 0; r < NR; ++r) s += g[r][c] * y[r];
            s = rsum_rows(s);
            const float cj = (c == 10 && tj == 0) ? -1.f : 0.f;
            const float zn = fmaxf(z[c] - tau * (cj + s), 0.f);
            zb[c] = 2.f * zn - z[c];
            z[c] = zn;
        }
        // y = relu(y + tau*(G zbar - b))
#pragma unroll
        for (int r = 0; r < NR; ++r) {
            float s = 0.f;
#pragma unroll
            for (int c = 0; c < NC; ++c) s += g[r][c] * zb[c];
            s = rsum_cols(s);
            y[r] = fmaxf(y[r] + tau * (s - bl[r]), 0.f);
        }
    }

    // ---- alpha map: x0[c] = z[c] (c<10 are the x components) ----
    float dvec[10];
#pragma unroll
    for (int c = 0; c < 10; ++c) {
        const int j = tj + 8 * c;
        dvec[c] = x_hat[(size_t)p * N_ACT + j] - z[c];
    }
    const float FINF = __builtin_inff();
    float amin = FINF;
#pragma unroll
    for (int r = 0; r < NR; ++r) {
        float ax = 0.f, ad = 0.f;
#pragma unroll
        for (int c = 0; c < 10; ++c) {
            ax += g[r][c] * z[c];
            ad += g[r][c] * dvec[c];
        }
        ax = rsum_cols(ax);
        ad = rsum_cols(ad);
        if (ti + 8 * r < M_CON) {
            const float slack = fmaxf(bl[r] - ax, 0.f);
            const float a = (ad > 0.f) ? slack / (ad + 1e-12f) : FINF;
            amin = fminf(amin, a);
        }
    }
    amin = fminf(amin, __shfl_xor(amin, 8, 64));
    amin = fminf(amin, __shfl_xor(amin, 16, 64));
    amin = fminf(amin, __shfl_xor(amin, 32, 64));

    float alpha = (amin < FINF) ? amin : 1.0f;
    alpha = fminf(fmaxf(alpha - 1e-9f, 0.f), 1.0f);

    if (ti == 0) {
#pragma unroll
        for (int c = 0; c < 10; ++c) {
            const int j = tj + 8 * c;
            out[(size_t)p * N_ACT + j] = fmaxf(z[c] + alpha * dvec[c], 0.f);
        }
    }
}

extern "C" void kernel_launch(void* const* d_in, const int* in_sizes, int n_in,
                              void* d_out, int out_size, void* d_ws, size_t ws_size,
                              hipStream_t stream) {
    const float* x_hat = (const float*)d_in[0];
    const float* A     = (const float*)d_in[1];
    const float* b     = (const float*)d_in[2];
    float* out = (float*)d_out;
    const int P = in_sizes[0] / N_ACT;   // B*S = 1024
    cheby_proj_kernel<<<P, 64, 0, stream>>>(x_hat, A, b, out);
}